// Round 7
// baseline (169.908 us; speedup 1.0000x reference)
//
#include <hip/hip_runtime.h>

// PooledMSELoss: mean((box9(pred) - box9(target))^2) = mean(box9(pred-tgt)^2)
// B,C,T,H,W = 4,2,8,512,512 fp32; POOL=9, zero pad on H,W, /81 per smooth.
//
// R7: byte-minimal. R1-R6 all moved ~2x compulsory bytes at a ~4 TB/s
// bytes-into-CU wall (MLP~1/wave in every compiled form). This version
// stages d = pred-tgt ONCE per tile into LDS (72x264 of a 64x256 out-tile,
// amp 1.16x -> 156 MB total), then does vertical+horizontal box sums fully
// LDS-resident. 512-thread blocks, 75KB LDS -> 2 blocks/CU, 16 waves/CU.

constexpr int Hh  = 512;
constexpr int Ww  = 512;
constexpr int PAD = 4;             // POOL/2
constexpr int TR  = 64;            // out rows per tile
constexpr int TC  = 256;           // out cols per tile
constexpr int SR  = TR + 2 * PAD;  // 72 staged rows
constexpr int STRIDE = TC + 2 * PAD + 4;  // 268 floats per LDS row

__global__ __launch_bounds__(512, 4)
void pooled_mse_kernel(const float* __restrict__ pred,
                       const float* __restrict__ tgt,
                       float* __restrict__ out) {
    __shared__ float d[SR * STRIDE];   // 77,184 B; s9 overlaid later
    __shared__ float wsum[8];

    const int tid = threadIdx.x;

    // Bijective XCD swizzle (1024 % 8 == 0): adjacent tiles (shared halo
    // rows/cols) stay on one XCD's L2.
    const int wg  = (blockIdx.x & 7) * 128 + (blockIdx.x >> 3);
    const int img = wg >> 4;               // 16 tiles per image
    const int t16 = wg & 15;
    const int sy  = (t16 >> 1) * TR;       // tile origin row
    const int cx  = (t16 & 1) * TC;        // tile origin col

    const float* pb = pred + (size_t)img * Hh * Ww;
    const float* tb = tgt  + (size_t)img * Hh * Ww;

    // ---- Stage main: 72 rows x 256 cols as float4, 9 independent iters ----
    {
        const int c4 = (tid & 63) * 4;     // col within tile (0,4,..,252)
        const int r0 = tid >> 6;           // 0..7
        #pragma unroll
        for (int it = 0; it < 9; ++it) {
            int r  = r0 + 8 * it;          // staged row 0..71
            int y  = sy - PAD + r;
            int yc = y < 0 ? 0 : (y > Hh - 1 ? Hh - 1 : y);
            float mk = ((unsigned)y < (unsigned)Hh) ? 1.0f : 0.0f;
            const float4 a = *(const float4*)(pb + (size_t)yc * Ww + cx + c4);
            const float4 b = *(const float4*)(tb + (size_t)yc * Ww + cx + c4);
            float4 dd;
            dd.x = (a.x - b.x) * mk; dd.y = (a.y - b.y) * mk;
            dd.z = (a.z - b.z) * mk; dd.w = (a.w - b.w) * mk;
            *(float4*)&d[r * STRIDE + PAD + c4] = dd;
        }
    }
    // ---- Stage halo cols: 4 left + 4 right, 72 rows (288 float2 slots) ----
    if (tid < 288) {
        int r = tid >> 2, q = tid & 3;
        int j0 = (q & 1) * 2 + ((q < 2) ? 0 : 260);     // staged col
        int x0 = cx - PAD + j0;                         // image col
        int y  = sy - PAD + r;
        int yc = y < 0 ? 0 : (y > Hh - 1 ? Hh - 1 : y);
        float my = ((unsigned)y < (unsigned)Hh) ? 1.0f : 0.0f;
        int x0c = x0 < 0 ? 0 : (x0 > Ww - 1 ? Ww - 1 : x0);
        int x1c = x0 + 1 < 0 ? 0 : (x0 + 1 > Ww - 1 ? Ww - 1 : x0 + 1);
        float m0 = ((unsigned)x0 < (unsigned)Ww) ? my : 0.0f;
        float m1 = ((unsigned)(x0 + 1) < (unsigned)Ww) ? my : 0.0f;
        float a0 = (pb[(size_t)yc * Ww + x0c] - tb[(size_t)yc * Ww + x0c]) * m0;
        float a1 = (pb[(size_t)yc * Ww + x1c] - tb[(size_t)yc * Ww + x1c]) * m1;
        d[r * STRIDE + j0]     = a0;
        d[r * STRIDE + j0 + 1] = a1;
    }
    __syncthreads();

    // ---- Vertical 9-sums (all from LDS) ----
    // Main: thread (cp = tid&127, g = tid>>7) owns staged cols 4+2cp..+1,
    // out rows 16g..16g+15; needs d rows 16g..16g+23.
    const int cp = tid & 127;
    const int g  = tid >> 7;
    const int jc = PAD + 2 * cp;
    float2 v[16];
    #pragma unroll
    for (int k = 0; k < 16; ++k) v[k] = make_float2(0.0f, 0.0f);
    #pragma unroll
    for (int m = 0; m < 24; ++m) {
        float2 dd = *(const float2*)&d[(16 * g + m) * STRIDE + jc];
        #pragma unroll
        for (int k = 0; k < 16; ++k)
            if (m >= k && m <= k + 8) { v[k].x += dd.x; v[k].y += dd.y; }
    }
    // Halo cols' vertical sums: thread -> (row hr = tid>>3, col hq = tid&7).
    const int hr = tid >> 3;
    const int hq = tid & 7;
    const int hj = (hq < 4) ? hq : 256 + hq;   // 0..3, 260..263
    float hv = 0.0f;
    #pragma unroll
    for (int m = 0; m < 9; ++m) hv += d[(hr + m) * STRIDE + hj];
    __syncthreads();

    // ---- s9 overlay (in place over d rows 0..63) ----
    #pragma unroll
    for (int k = 0; k < 16; ++k)
        *(float2*)&d[(16 * g + k) * STRIDE + jc] = v[k];
    d[hr * STRIDE + hj] = hv;
    __syncthreads();

    // ---- Horizontal 9-sums + accumulate squares ----
    float acc = 0.0f;
    #pragma unroll
    for (int k = 0; k < 16; ++k) {
        const int R = 16 * g + k;
        float s[10];
        #pragma unroll
        for (int u = 0; u < 5; ++u) {
            float2 w = *(const float2*)&d[R * STRIDE + 2 * cp + 2 * u];
            s[2 * u] = w.x; s[2 * u + 1] = w.y;
        }
        float t8 = s[1];
        #pragma unroll
        for (int q = 2; q <= 8; ++q) t8 += s[q];
        float o0 = t8 + s[0];   // out col cx + 2cp
        float o1 = t8 + s[9];   // out col cx + 2cp + 1
        acc = fmaf(o0, o0, acc);
        acc = fmaf(o1, o1, acc);
    }

    // ---- Reduce: wave shuffle, cross-wave via LDS, one atomic ----
    #pragma unroll
    for (int off = 32; off > 0; off >>= 1)
        acc += __shfl_down(acc, off, 64);

    const int wid = tid >> 6, lane = tid & 63;
    if (lane == 0) wsum[wid] = acc;
    __syncthreads();
    if (tid == 0) {
        float b = 0.0f;
        #pragma unroll
        for (int w = 0; w < 8; ++w) b += wsum[w];
        const float scale = 1.0f / (81.0f * 81.0f * 16777216.0f);
        atomicAdd(out, b * scale);
    }
}

extern "C" void kernel_launch(void* const* d_in, const int* in_sizes, int n_in,
                              void* d_out, int out_size, void* d_ws, size_t ws_size,
                              hipStream_t stream) {
    const float* pred = (const float*)d_in[0];
    const float* tgt  = (const float*)d_in[1];
    float* out = (float*)d_out;

    // d_out is re-poisoned to 0xAA before every timed launch.
    hipMemsetAsync(out, 0, sizeof(float), stream);

    const int nblocks = 64 * 16;   // 64 images * (8 x 2) tiles = 1024
    pooled_mse_kernel<<<nblocks, 512, 0, stream>>>(pred, tgt, out);
}

// Round 8
// 155.335 us; speedup vs baseline: 1.0938x; 1.0938x over previous
//
#include <hip/hip_runtime.h>

// PooledMSELoss: mean((box9(pred) - box9(target))^2) = mean(box9(pred-tgt)^2)
// B,C,T,H,W = 4,2,8,512,512 fp32; POOL=9, zero pad on H,W, /81 per smooth.
//
// R8: R7 structure (stage d=pred-tgt once into LDS, then LDS-resident
// vertical+horizontal box sums) with occupancy as the lever: TR 64->32
// shrinks LDS 77->43KB -> 3 blocks/CU (24 waves vs R7's 10.6). Model from
// R1-R7: throughput = resident-waves x in-flight-bytes/wave at ~1us
// effective latency; byte volume x throughput sets time.

constexpr int Hh  = 512;
constexpr int Ww  = 512;
constexpr int PAD = 4;             // POOL/2
constexpr int TR  = 32;            // out rows per tile
constexpr int TC  = 256;           // out cols per tile
constexpr int SR  = TR + 2 * PAD;  // 40 staged rows
constexpr int STRIDE = TC + 2 * PAD + 4;  // 268 floats per LDS row

__global__ __launch_bounds__(512, 6)
void pooled_mse_kernel(const float* __restrict__ pred,
                       const float* __restrict__ tgt,
                       float* __restrict__ out) {
    __shared__ float d[SR * STRIDE];   // 42,880 B; s9 overlaid in place
    __shared__ float wsum[8];

    const int tid = threadIdx.x;

    // Bijective XCD swizzle (2048 % 8 == 0): adjacent tiles (shared halos)
    // stay on one XCD's L2.
    const int wg  = (blockIdx.x & 7) * 256 + (blockIdx.x >> 3);
    const int img = wg >> 5;               // 32 tiles per image
    const int t32 = wg & 31;
    const int sy  = (t32 >> 1) * TR;       // tile origin row
    const int cx  = (t32 & 1) * TC;        // tile origin col

    const float* pb = pred + (size_t)img * Hh * Ww;
    const float* tb = tgt  + (size_t)img * Hh * Ww;

    // ---- Stage main: 40 rows x 256 cols as float4, 5 independent iters ----
    {
        const int c4 = (tid & 63) * 4;     // col within tile (0,4,..,252)
        const int r0 = tid >> 6;           // 0..7
        #pragma unroll
        for (int it = 0; it < 5; ++it) {
            int r  = r0 + 8 * it;          // staged row 0..39
            int y  = sy - PAD + r;
            int yc = y < 0 ? 0 : (y > Hh - 1 ? Hh - 1 : y);
            float mk = ((unsigned)y < (unsigned)Hh) ? 1.0f : 0.0f;
            const float4 a = *(const float4*)(pb + (size_t)yc * Ww + cx + c4);
            const float4 b = *(const float4*)(tb + (size_t)yc * Ww + cx + c4);
            float4 dd;
            dd.x = (a.x - b.x) * mk; dd.y = (a.y - b.y) * mk;
            dd.z = (a.z - b.z) * mk; dd.w = (a.w - b.w) * mk;
            *(float4*)&d[r * STRIDE + PAD + c4] = dd;
        }
    }
    // ---- Stage halo cols: 4 left + 4 right, 40 rows (160 float2 slots) ----
    if (tid < 160) {
        int r = tid >> 2, q = tid & 3;
        int j0 = (q & 1) * 2 + ((q < 2) ? 0 : 260);     // staged col
        int x0 = cx - PAD + j0;                         // image col
        int y  = sy - PAD + r;
        int yc = y < 0 ? 0 : (y > Hh - 1 ? Hh - 1 : y);
        float my = ((unsigned)y < (unsigned)Hh) ? 1.0f : 0.0f;
        int x0c = x0 < 0 ? 0 : (x0 > Ww - 1 ? Ww - 1 : x0);
        int x1c = x0 + 1 < 0 ? 0 : (x0 + 1 > Ww - 1 ? Ww - 1 : x0 + 1);
        float m0 = ((unsigned)x0 < (unsigned)Ww) ? my : 0.0f;
        float m1 = ((unsigned)(x0 + 1) < (unsigned)Ww) ? my : 0.0f;
        float a0 = (pb[(size_t)yc * Ww + x0c] - tb[(size_t)yc * Ww + x0c]) * m0;
        float a1 = (pb[(size_t)yc * Ww + x1c] - tb[(size_t)yc * Ww + x1c]) * m1;
        d[r * STRIDE + j0]     = a0;
        d[r * STRIDE + j0 + 1] = a1;
    }
    __syncthreads();

    // ---- Vertical 9-sums (all from LDS) ----
    // Thread (cp = tid&127, g = tid>>7) owns staged cols 4+2cp..+1 and
    // out rows 8g..8g+7; needs staged rows 8g..8g+15.
    const int cp = tid & 127;
    const int g  = tid >> 7;               // 0..3
    const int jc = PAD + 2 * cp;
    float2 v[8];
    #pragma unroll
    for (int k = 0; k < 8; ++k) v[k] = make_float2(0.0f, 0.0f);
    #pragma unroll
    for (int m = 0; m < 16; ++m) {
        float2 dd = *(const float2*)&d[(8 * g + m) * STRIDE + jc];
        #pragma unroll
        for (int k = 0; k < 8; ++k)
            if (m >= k && m <= k + 8) { v[k].x += dd.x; v[k].y += dd.y; }
    }
    // Halo cols' vertical sums: thread -> (row hr = tid>>3, col hq = tid&7).
    const int hr = tid >> 3;               // 0..63 (only <TR used)
    const int hq = tid & 7;
    const int hj = (hq < 4) ? hq : 256 + hq;   // 0..3, 260..263
    float hv = 0.0f;
    if (hr < TR) {
        #pragma unroll
        for (int m = 0; m < 9; ++m) hv += d[(hr + m) * STRIDE + hj];
    }
    __syncthreads();

    // ---- s9 overlay (in place over d rows 0..31) ----
    #pragma unroll
    for (int k = 0; k < 8; ++k)
        *(float2*)&d[(8 * g + k) * STRIDE + jc] = v[k];
    if (hr < TR) d[hr * STRIDE + hj] = hv;
    __syncthreads();

    // ---- Horizontal 9-sums + accumulate squares ----
    float acc = 0.0f;
    #pragma unroll
    for (int k = 0; k < 8; ++k) {
        const int R = 8 * g + k;
        float s[10];
        #pragma unroll
        for (int u = 0; u < 5; ++u) {
            float2 w = *(const float2*)&d[R * STRIDE + 2 * cp + 2 * u];
            s[2 * u] = w.x; s[2 * u + 1] = w.y;
        }
        float t8 = s[1];
        #pragma unroll
        for (int q = 2; q <= 8; ++q) t8 += s[q];
        float o0 = t8 + s[0];   // out col cx + 2cp
        float o1 = t8 + s[9];   // out col cx + 2cp + 1
        acc = fmaf(o0, o0, acc);
        acc = fmaf(o1, o1, acc);
    }

    // ---- Reduce: wave shuffle, cross-wave via LDS, one atomic ----
    #pragma unroll
    for (int off = 32; off > 0; off >>= 1)
        acc += __shfl_down(acc, off, 64);

    const int wid = tid >> 6, lane = tid & 63;
    if (lane == 0) wsum[wid] = acc;
    __syncthreads();
    if (tid == 0) {
        float b = 0.0f;
        #pragma unroll
        for (int w = 0; w < 8; ++w) b += wsum[w];
        const float scale = 1.0f / (81.0f * 81.0f * 16777216.0f);
        atomicAdd(out, b * scale);
    }
}

extern "C" void kernel_launch(void* const* d_in, const int* in_sizes, int n_in,
                              void* d_out, int out_size, void* d_ws, size_t ws_size,
                              hipStream_t stream) {
    const float* pred = (const float*)d_in[0];
    const float* tgt  = (const float*)d_in[1];
    float* out = (float*)d_out;

    // d_out is re-poisoned to 0xAA before every timed launch.
    hipMemsetAsync(out, 0, sizeof(float), stream);

    const int nblocks = 64 * (Hh / TR) * (Ww / TC);   // 64 * 16 * 2 = 2048
    pooled_mse_kernel<<<nblocks, 512, 0, stream>>>(pred, tgt, out);
}